// Round 4
// baseline (62.257 us; speedup 1.0000x reference)
//
#include <hip/hip_runtime.h>

// MidMaxPooling2D: x [16,256,256,64] f32, pool 2x2 stride 2 -> [16,128,128,64]
// out = 0.5*max(window) + 0.5*max(second_smallest(window), 0)
// R4: 4 outputs/thread (batch-split b, b+4, b+8, b+12) -> 16-deep MLP, nt ld/st.

#define B_  16
#define H_  256
#define W_  256
#define C_  64
#define CV_ (C_ / 4)                          // 16 vec4 per pixel
#define IN_B_STRIDE  (H_ * W_ * CV_)          // 1,048,576 vec4
#define OUT_Q        (4 * 128 * 128 * CV_)    // 1,048,576 vec4 (b = 0..3)

typedef float f32x4 __attribute__((ext_vector_type(4)));

__device__ __forceinline__ float midmax1(float a, float b, float c, float d) {
    float lo1 = fminf(a, b), hi1 = fmaxf(a, b);
    float lo2 = fminf(c, d), hi2 = fmaxf(c, d);
    float mx  = fmaxf(hi1, hi2);
    float ss  = fminf(fmaxf(lo1, lo2), fminf(hi1, hi2)); // 2nd smallest of 4
    float mid = fmaxf(ss, 0.0f);
    return 0.5f * (mx + mid);   // ALPHA = 0.5
}

__device__ __forceinline__ f32x4 midmax4(f32x4 a, f32x4 b, f32x4 c, f32x4 d) {
    f32x4 r;
    r.x = midmax1(a.x, b.x, c.x, d.x);
    r.y = midmax1(a.y, b.y, c.y, d.y);
    r.z = midmax1(a.z, b.z, c.z, d.z);
    r.w = midmax1(a.w, b.w, c.w, d.w);
    return r;
}

__global__ __launch_bounds__(256) void midmax_kernel(
        const f32x4* __restrict__ x, f32x4* __restrict__ out) {
    int idx = blockIdx.x * blockDim.x + threadIdx.x;   // 0 .. OUT_Q-1

    // idx = ((b*Ho + ho)*Wo + wo)*CV + cv, Ho=Wo=128, CV=16, b in 0..3
    int cv = idx & 15;
    int t  = idx >> 4;
    int wo = t & 127;
    t >>= 7;
    int ho = t & 127;
    int b  = t >> 7;

    long base0 = (long)b * IN_B_STRIDE
               + (long)(2 * ho) * (W_ * CV_)
               + (2 * wo) * CV_
               + cv;

    f32x4 v[4][4];
    #pragma unroll
    for (int g = 0; g < 4; ++g) {
        long base = base0 + (long)g * (4L * IN_B_STRIDE);
        v[g][0] = __builtin_nontemporal_load(x + base);
        v[g][1] = __builtin_nontemporal_load(x + base + CV_);
        v[g][2] = __builtin_nontemporal_load(x + base + W_ * CV_);
        v[g][3] = __builtin_nontemporal_load(x + base + W_ * CV_ + CV_);
    }

    #pragma unroll
    for (int g = 0; g < 4; ++g) {
        f32x4 r = midmax4(v[g][0], v[g][1], v[g][2], v[g][3]);
        __builtin_nontemporal_store(r, out + idx + (long)g * OUT_Q);
    }
}

extern "C" void kernel_launch(void* const* d_in, const int* in_sizes, int n_in,
                              void* d_out, int out_size, void* d_ws, size_t ws_size,
                              hipStream_t stream) {
    const f32x4* x = (const f32x4*)d_in[0];
    f32x4* out = (f32x4*)d_out;
    int block = 256;
    int grid = OUT_Q / block;   // 4096
    midmax_kernel<<<grid, block, 0, stream>>>(x, out);
}

// Round 5
// 58.001 us; speedup vs baseline: 1.0734x; 1.0734x over previous
//
#include <hip/hip_runtime.h>

// MidMaxPooling2D: x [16,256,256,64] f32, pool 2x2 stride 2 -> [16,128,128,64]
// out = 0.5*max(window) + 0.5*max(second_smallest(window), 0)
// R5: depth-8 MLP via ADJACENT-ho split (4 consecutive input rows per thread),
//     nt ld/st. Same thread count as R3 (2M), better DRAM stream locality.

#define H_  256
#define W_  256
#define C_  64
#define CV_ (C_ / 4)                   // 16 vec4 per pixel
#define ROW_ (W_ * CV_)                // 4096 vec4 per input row
#define OROW_ (128 * CV_)              // 2048 vec4 per output row
#define IN_B_STRIDE  (H_ * ROW_)       // 1,048,576 vec4

typedef float f32x4 __attribute__((ext_vector_type(4)));

__device__ __forceinline__ float midmax1(float a, float b, float c, float d) {
    float lo1 = fminf(a, b), hi1 = fmaxf(a, b);
    float lo2 = fminf(c, d), hi2 = fmaxf(c, d);
    float mx  = fmaxf(hi1, hi2);
    float ss  = fminf(fmaxf(lo1, lo2), fminf(hi1, hi2)); // 2nd smallest of 4
    float mid = fmaxf(ss, 0.0f);
    return 0.5f * (mx + mid);   // ALPHA = 0.5
}

__device__ __forceinline__ f32x4 midmax4(f32x4 a, f32x4 b, f32x4 c, f32x4 d) {
    f32x4 r;
    r.x = midmax1(a.x, b.x, c.x, d.x);
    r.y = midmax1(a.y, b.y, c.y, d.y);
    r.z = midmax1(a.z, b.z, c.z, d.z);
    r.w = midmax1(a.w, b.w, c.w, d.w);
    return r;
}

__global__ __launch_bounds__(256) void midmax_kernel(
        const f32x4* __restrict__ x, f32x4* __restrict__ out) {
    int idx = blockIdx.x * blockDim.x + threadIdx.x;   // 0 .. 2,097,151

    // idx = ((b*64 + hp)*128 + wo)*16 + cv ; output rows 2hp and 2hp+1
    int cv = idx & 15;
    int t  = idx >> 4;
    int wo = t & 127;
    t >>= 7;
    int hp = t & 63;
    int b  = t >> 6;

    // input rows 4hp .. 4hp+3 (256 KB contiguous region)
    long base1 = (long)b * IN_B_STRIDE
               + (long)(4 * hp) * ROW_
               + (2 * wo) * CV_
               + cv;
    long base2 = base1 + 2L * ROW_;

    f32x4 a00 = __builtin_nontemporal_load(x + base1);
    f32x4 a01 = __builtin_nontemporal_load(x + base1 + CV_);
    f32x4 a10 = __builtin_nontemporal_load(x + base1 + ROW_);
    f32x4 a11 = __builtin_nontemporal_load(x + base1 + ROW_ + CV_);
    f32x4 b00 = __builtin_nontemporal_load(x + base2);
    f32x4 b01 = __builtin_nontemporal_load(x + base2 + CV_);
    f32x4 b10 = __builtin_nontemporal_load(x + base2 + ROW_);
    f32x4 b11 = __builtin_nontemporal_load(x + base2 + ROW_ + CV_);

    f32x4 r1 = midmax4(a00, a01, a10, a11);
    f32x4 r2 = midmax4(b00, b01, b10, b11);

    // output rows 2hp, 2hp+1
    long oidx = ((long)(b * 128 + 2 * hp) * 128 + wo) * CV_ + cv;
    __builtin_nontemporal_store(r1, out + oidx);
    __builtin_nontemporal_store(r2, out + oidx + OROW_);
}

extern "C" void kernel_launch(void* const* d_in, const int* in_sizes, int n_in,
                              void* d_out, int out_size, void* d_ws, size_t ws_size,
                              hipStream_t stream) {
    const f32x4* x = (const f32x4*)d_in[0];
    f32x4* out = (f32x4*)d_out;
    int block = 256;
    int grid = (16 * 64 * 128 * CV_) / block;   // 8192
    midmax_kernel<<<grid, block, 0, stream>>>(x, out);
}

// Round 6
// 57.511 us; speedup vs baseline: 1.0825x; 1.0085x over previous
//
#include <hip/hip_runtime.h>

// MidMaxPooling2D: x [16,256,256,64] f32, pool 2x2 stride 2 -> [16,128,128,64]
// out = 0.5*max(window) + 0.5*max(second_smallest(window), 0)
// R6: R5 structure (adjacent-ho split, depth-8 MLP, nt LOADS) but CACHED
//     stores — let the 67MB output stream buffer in L2/L3 and drain lazily,
//     overlapping the flush with the next iteration's read phase.

#define H_  256
#define W_  256
#define C_  64
#define CV_ (C_ / 4)                   // 16 vec4 per pixel
#define ROW_ (W_ * CV_)                // 4096 vec4 per input row
#define OROW_ (128 * CV_)              // 2048 vec4 per output row
#define IN_B_STRIDE  (H_ * ROW_)       // 1,048,576 vec4

typedef float f32x4 __attribute__((ext_vector_type(4)));

__device__ __forceinline__ float midmax1(float a, float b, float c, float d) {
    float lo1 = fminf(a, b), hi1 = fmaxf(a, b);
    float lo2 = fminf(c, d), hi2 = fmaxf(c, d);
    float mx  = fmaxf(hi1, hi2);
    float ss  = fminf(fmaxf(lo1, lo2), fminf(hi1, hi2)); // 2nd smallest of 4
    float mid = fmaxf(ss, 0.0f);
    return 0.5f * (mx + mid);   // ALPHA = 0.5
}

__device__ __forceinline__ f32x4 midmax4(f32x4 a, f32x4 b, f32x4 c, f32x4 d) {
    f32x4 r;
    r.x = midmax1(a.x, b.x, c.x, d.x);
    r.y = midmax1(a.y, b.y, c.y, d.y);
    r.z = midmax1(a.z, b.z, c.z, d.z);
    r.w = midmax1(a.w, b.w, c.w, d.w);
    return r;
}

__global__ __launch_bounds__(256) void midmax_kernel(
        const f32x4* __restrict__ x, f32x4* __restrict__ out) {
    int idx = blockIdx.x * blockDim.x + threadIdx.x;   // 0 .. 2,097,151

    // idx = ((b*64 + hp)*128 + wo)*16 + cv ; output rows 2hp and 2hp+1
    int cv = idx & 15;
    int t  = idx >> 4;
    int wo = t & 127;
    t >>= 7;
    int hp = t & 63;
    int b  = t >> 6;

    // input rows 4hp .. 4hp+3 (contiguous 4-row region)
    long base1 = (long)b * IN_B_STRIDE
               + (long)(4 * hp) * ROW_
               + (2 * wo) * CV_
               + cv;
    long base2 = base1 + 2L * ROW_;

    f32x4 a00 = __builtin_nontemporal_load(x + base1);
    f32x4 a01 = __builtin_nontemporal_load(x + base1 + CV_);
    f32x4 a10 = __builtin_nontemporal_load(x + base1 + ROW_);
    f32x4 a11 = __builtin_nontemporal_load(x + base1 + ROW_ + CV_);
    f32x4 b00 = __builtin_nontemporal_load(x + base2);
    f32x4 b01 = __builtin_nontemporal_load(x + base2 + CV_);
    f32x4 b10 = __builtin_nontemporal_load(x + base2 + ROW_);
    f32x4 b11 = __builtin_nontemporal_load(x + base2 + ROW_ + CV_);

    f32x4 r1 = midmax4(a00, a01, a10, a11);
    f32x4 r2 = midmax4(b00, b01, b10, b11);

    // output rows 2hp, 2hp+1 — CACHED stores (no nt): drain via L2/L3 lazily
    long oidx = ((long)(b * 128 + 2 * hp) * 128 + wo) * CV_ + cv;
    out[oidx] = r1;
    out[oidx + OROW_] = r2;
}

extern "C" void kernel_launch(void* const* d_in, const int* in_sizes, int n_in,
                              void* d_out, int out_size, void* d_ws, size_t ws_size,
                              hipStream_t stream) {
    const f32x4* x = (const f32x4*)d_in[0];
    f32x4* out = (f32x4*)d_out;
    int block = 256;
    int grid = (16 * 64 * 128 * CV_) / block;   // 8192
    midmax_kernel<<<grid, block, 0, stream>>>(x, out);
}